// Round 5
// baseline (11.446 us; speedup 1.0000x reference)
//
#include <hip/hip_runtime.h>

// Analytic reduction of the 3-qubit circuit:
//   CNOT(0,1) and CNOT(1,2) preserve the b0 index -> commute with Z_0.
//   Qubit 0 state = RY(theta0)*RY(p0)|0> = [cos((p0+t0)/2), sin((p0+t0)/2)]
//   <Z_0> = cos^2 - sin^2 = cos(p0 + theta0).
// So out[i] = cos(patches[3*i] + theta[0]). Pure memory-bound streaming.
// History: r1 4/thr plain cosf = 10.45; r3 8/thr + NT + __cosf = 12.55;
// r4 4/thr plain __cosf = 10.37. This round: 8/thr plain __cosf (isolates
// NT vs structure as r3's regression cause).

__global__ __launch_bounds__(256) void qconv3_vec8_kernel(
    const float* __restrict__ patches,   // [B,3] flat
    const float* __restrict__ theta,     // [3]
    float* __restrict__ out,             // [B]
    int n8)                              // B/8
{
    int t = blockIdx.x * blockDim.x + threadIdx.x;
    if (t >= n8) return;
    float t0 = theta[0];
    const float4* p = reinterpret_cast<const float4*>(patches) + 6 * (size_t)t;
    // 8 patches = 24 floats = 6 float4s; column-0 at flat 0,3,6,9,12,15,18,21
    float4 v0 = p[0];
    float4 v1 = p[1];
    float4 v2 = p[2];
    float4 v3 = p[3];
    float4 v4 = p[4];
    float4 v5 = p[5];
    float4 oa, ob;
    oa.x = __cosf(v0.x + t0);   // flat 24t+0
    oa.y = __cosf(v0.w + t0);   // flat 24t+3
    oa.z = __cosf(v1.z + t0);   // flat 24t+6
    oa.w = __cosf(v2.y + t0);   // flat 24t+9
    ob.x = __cosf(v3.x + t0);   // flat 24t+12
    ob.y = __cosf(v3.w + t0);   // flat 24t+15
    ob.z = __cosf(v4.z + t0);   // flat 24t+18
    ob.w = __cosf(v5.y + t0);   // flat 24t+21
    float4* o = reinterpret_cast<float4*>(out) + 2 * (size_t)t;
    o[0] = oa;
    o[1] = ob;
}

// Scalar fallback for any tail (B=2097152 divisible by 8, so unused here).
__global__ __launch_bounds__(256) void qconv3_scalar_kernel(
    const float* __restrict__ patches,
    const float* __restrict__ theta,
    float* __restrict__ out,
    int n, int start)
{
    int i = start + blockIdx.x * blockDim.x + threadIdx.x;
    if (i >= n) return;
    out[i] = __cosf(patches[3 * (size_t)i] + theta[0]);
}

extern "C" void kernel_launch(void* const* d_in, const int* in_sizes, int n_in,
                              void* d_out, int out_size, void* d_ws, size_t ws_size,
                              hipStream_t stream) {
    const float* patches = (const float*)d_in[0];
    const float* theta   = (const float*)d_in[1];
    float* out = (float*)d_out;

    int n  = out_size;          // B
    int n8 = n / 8;
    if (n8 > 0) {
        int blocks = (n8 + 255) / 256;
        qconv3_vec8_kernel<<<blocks, 256, 0, stream>>>(patches, theta, out, n8);
    }
    int tail = n - n8 * 8;
    if (tail > 0) {
        qconv3_scalar_kernel<<<1, 256, 0, stream>>>(patches, theta, out, n, n8 * 8);
    }
}

// Round 6
// 10.699 us; speedup vs baseline: 1.0698x; 1.0698x over previous
//
#include <hip/hip_runtime.h>

// Analytic reduction: out[i] = cos(patches[3*i] + theta[0]).
// This round: fully-coalesced loads (block-strided unit-stride float4) +
// LDS repack so stores stay coalesced. Probes whether the stride-48B load
// pattern's 3x L1/L2 request amplification was costing (~1 us) or whether
// the residual over the 4.9 us BW floor is launch/ramp (then r4 = roofline).
// History: r1 4/thr cosf 10.45 | r3 8/thr NT __cosf 12.55 |
//          r4 4/thr __cosf 10.37 (best) | r5 8/thr __cosf 11.45.

__global__ __launch_bounds__(256) void qconv3_lds_kernel(
    const float* __restrict__ patches,   // [B,3] flat
    const float* __restrict__ theta,     // [3]
    float* __restrict__ out,             // [B]
    int nblocks_work)                    // total float4-groups = B*3/4/... (unused guard)
{
    __shared__ float lds[1024];          // 1024 outputs per block
    const int tid = threadIdx.x;
    const float t0 = theta[0];
    // Block handles 1024 patches = 3072 floats = 768 float4s.
    const size_t base4 = (size_t)blockIdx.x * 768;   // float4 index base
    const float4* p = reinterpret_cast<const float4*>(patches);

    #pragma unroll
    for (int k = 0; k < 3; ++k) {
        int m = k * 256 + tid;            // local float4 index [0,768)
        float4 v = p[base4 + m];          // unit-stride across the block
        int F = 4 * m;                    // local flat float offset
        int r = m % 3;                    // (4m)%3 == m%3
        int q = F / 3;                    // compiler magic-mul
        // every float4 contributes element j = 3-r -> local out q+1
        float e1 = (r == 0) ? v.w : ((r == 1) ? v.z : v.y);
        lds[q + 1] = __cosf(e1 + t0);
        if (r == 0) {                     // additionally element 0 -> local out q
            lds[q] = __cosf(v.x + t0);
        }
    }
    __syncthreads();
    // coalesced store: 256 float4 = 1024 floats
    float4 o;
    o.x = lds[4 * tid + 0];
    o.y = lds[4 * tid + 1];
    o.z = lds[4 * tid + 2];
    o.w = lds[4 * tid + 3];
    reinterpret_cast<float4*>(out)[(size_t)blockIdx.x * 256 + tid] = o;
}

// Scalar fallback for any tail (B=2097152 divisible by 1024, so unused here).
__global__ __launch_bounds__(256) void qconv3_scalar_kernel(
    const float* __restrict__ patches,
    const float* __restrict__ theta,
    float* __restrict__ out,
    int n, int start)
{
    int i = start + blockIdx.x * blockDim.x + threadIdx.x;
    if (i >= n) return;
    out[i] = __cosf(patches[3 * (size_t)i] + theta[0]);
}

extern "C" void kernel_launch(void* const* d_in, const int* in_sizes, int n_in,
                              void* d_out, int out_size, void* d_ws, size_t ws_size,
                              hipStream_t stream) {
    const float* patches = (const float*)d_in[0];
    const float* theta   = (const float*)d_in[1];
    float* out = (float*)d_out;

    int n = out_size;                 // B
    int nb = n / 1024;                // full blocks of 1024 patches
    if (nb > 0) {
        qconv3_lds_kernel<<<nb, 256, 0, stream>>>(patches, theta, out, nb);
    }
    int tail = n - nb * 1024;
    if (tail > 0) {
        qconv3_scalar_kernel<<<(tail + 255) / 256, 256, 0, stream>>>(
            patches, theta, out, n, nb * 1024);
    }
}

// Round 7
// 10.359 us; speedup vs baseline: 1.1050x; 1.0329x over previous
//
#include <hip/hip_runtime.h>

// Analytic reduction of the 3-qubit circuit:
//   CNOT(0,1) and CNOT(1,2) preserve the b0 index -> commute with Z_0.
//   Qubit 0 state = RY(theta0)*RY(p0)|0> = [cos((p0+t0)/2), sin((p0+t0)/2)]
//   <Z_0> = cos^2 - sin^2 = cos(p0 + theta0).
// So out[i] = cos(patches[3*i] + theta[0]). Pure memory-bound streaming.
//
// Final form = round-4 best (10.37 us). Experiment matrix:
//   r1 4/thr cosf            10.45
//   r4 4/thr __cosf          10.37  <- best
//   r5 8/thr __cosf          11.45  (fewer waves -> worse latency hiding)
//   r3 8/thr NT __cosf       12.55  (NT bypass hurts; L1/L2 reuse matters)
//   r6 coalesced+LDS repack  10.70  (request amplification was NOT the cost)
// Floor: 32 MB @ ~6.6 TB/s = 4.9 us + launch/ramp ~5.5 us. Structural floor.

__global__ __launch_bounds__(256) void qconv3_vec4_kernel(
    const float* __restrict__ patches,   // [B,3] flat
    const float* __restrict__ theta,     // [3]
    float* __restrict__ out,             // [B]
    int n4)                              // B/4
{
    int t = blockIdx.x * blockDim.x + threadIdx.x;
    if (t >= n4) return;
    float t0 = theta[0];
    const float4* p = reinterpret_cast<const float4*>(patches) + 3 * (size_t)t;
    float4 v0 = p[0];   // patches[12t+0 .. 12t+3]
    float4 v1 = p[1];   // patches[12t+4 .. 12t+7]
    float4 v2 = p[2];   // patches[12t+8 .. 12t+11]
    float4 o;
    o.x = __cosf(v0.x + t0);   // patch 4t+0, elem 0 -> flat 12t+0
    o.y = __cosf(v0.w + t0);   // patch 4t+1, elem 0 -> flat 12t+3
    o.z = __cosf(v1.z + t0);   // patch 4t+2, elem 0 -> flat 12t+6
    o.w = __cosf(v2.y + t0);   // patch 4t+3, elem 0 -> flat 12t+9
    reinterpret_cast<float4*>(out)[t] = o;
}

// Scalar fallback for any tail (B=2097152 divisible by 4, so unused here).
__global__ __launch_bounds__(256) void qconv3_scalar_kernel(
    const float* __restrict__ patches,
    const float* __restrict__ theta,
    float* __restrict__ out,
    int n, int start)
{
    int i = start + blockIdx.x * blockDim.x + threadIdx.x;
    if (i >= n) return;
    out[i] = __cosf(patches[3 * (size_t)i] + theta[0]);
}

extern "C" void kernel_launch(void* const* d_in, const int* in_sizes, int n_in,
                              void* d_out, int out_size, void* d_ws, size_t ws_size,
                              hipStream_t stream) {
    const float* patches = (const float*)d_in[0];
    const float* theta   = (const float*)d_in[1];
    float* out = (float*)d_out;

    int n  = out_size;          // B
    int n4 = n / 4;
    if (n4 > 0) {
        int blocks = (n4 + 255) / 256;
        qconv3_vec4_kernel<<<blocks, 256, 0, stream>>>(patches, theta, out, n4);
    }
    int tail = n - n4 * 4;
    if (tail > 0) {
        qconv3_scalar_kernel<<<1, 256, 0, stream>>>(patches, theta, out, n, n4 * 4);
    }
}